// Round 2
// baseline (194.741 us; speedup 1.0000x reference)
//
#include <hip/hip_runtime.h>

#define BB 8
#define NN 32
#define LL 64
#define NGROUP (BB * NN * NN)   // 8192 (b,i,j) groups
#define NBLOCK (NGROUP / 4)     // 2048 blocks, 4 waves (groups) each

// broadcast lane l's value (l compile-time constant) via v_readlane
__device__ __forceinline__ float rl(float x, int l) {
    return __uint_as_float(__builtin_amdgcn_readlane(__float_as_uint(x), l));
}

extern "C" __global__ __launch_bounds__(256, 4)
void fsmre_main(const float* __restrict__ probs, const int* __restrict__ target,
                float* __restrict__ pce, unsigned long long* __restrict__ pcnt) {
    const int lane = threadIdx.x & 63;
    const int wv   = threadIdx.x >> 6;
    const int wid  = blockIdx.x * 4 + wv;          // (b*N + i)*N + j
    const int j = wid & (NN - 1);
    const int i = (wid >> 5) & (NN - 1);

    float        s    = 0.0f;
    unsigned int ccnt = 0, allc = 0;

    if (i != j) {
        const float4* base4 = reinterpret_cast<const float4*>(probs + (size_t)wid * (LL * LL));
        const int tgt = target[wid * LL + lane];            // coalesced, hoisted

        // load the whole 16KiB group: 16 x dwordx4 in flight per wave
        float4 vf[16];
        #pragma unroll
        for (int t = 0; t < 16; ++t) vf[t] = base4[t * 64 + lane];

        // lane k holds columns 4*(k&15)..+3 of row 4t + (k>>4)
        const int q = lane >> 4;                            // tile-row of this lane
        unsigned long long ismax_mask = 0ull;               // bit r: diag==max for row r
        float mydiag = 0.5f;                                // lane l ends with diag of row l

        #pragma unroll
        for (int t = 0; t < 16; ++t) {
            const float4 v = vf[t];
            // diag of row 4t+q sits at lane 16q+t, element q
            const float d0 = rl(v.x, t);
            const float d1 = rl(v.y, 16 + t);
            const float d2 = rl(v.z, 32 + t);
            const float d3 = rl(v.w, 48 + t);
            const float d  = q == 0 ? d0 : (q == 1 ? d1 : (q == 2 ? d2 : d3));
            const float m  = fmaxf(fmaxf(v.x, v.y), fmaxf(v.z, v.w));
            const unsigned long long bal = __ballot(m > d);  // 16-bit field per row
            unsigned int nib = 0;
            if ((bal & 0x000000000000FFFFull) == 0) nib |= 1u;
            if ((bal & 0x00000000FFFF0000ull) == 0) nib |= 2u;
            if ((bal & 0x0000FFFF00000000ull) == 0) nib |= 4u;
            if ((bal & 0xFFFF000000000000ull) == 0) nib |= 8u;
            ismax_mask |= (unsigned long long)nib << (4 * t);
            // deposit diag of row 4t+q into lane 4t+q
            if (lane == 4 * t)     mydiag = d0;
            if (lane == 4 * t + 1) mydiag = d1;
            if (lane == 4 * t + 2) mydiag = d2;
            if (lane == 4 * t + 3) mydiag = d3;
        }

        const int  myismax = (int)((ismax_mask >> lane) & 1ull);
        const bool correct = ((myismax != 0) == (tgt == 1));
        s = tgt ? -logf(mydiag) : -log1pf(-mydiag);
        #pragma unroll
        for (int off = 32; off > 0; off >>= 1) s += __shfl_xor(s, off, 64);
        const unsigned long long cb = __ballot(correct);
        ccnt = (unsigned int)__popcll(cb);
        allc = (cb == ~0ull) ? 1u : 0u;
    }

    __shared__ float ls[4];
    __shared__ unsigned long long lc[4];
    if (lane == 0) {
        ls[wv] = s;
        lc[wv] = ((unsigned long long)allc << 32) | (unsigned long long)ccnt;
    }
    __syncthreads();
    if (threadIdx.x == 0) {
        pce[blockIdx.x]  = ls[0] + ls[1] + ls[2] + ls[3];
        pcnt[blockIdx.x] = lc[0] + lc[1] + lc[2] + lc[3];
    }
}

extern "C" __global__ __launch_bounds__(256)
void fsmre_final(const float* __restrict__ pce, const unsigned long long* __restrict__ pcnt,
                 float* __restrict__ out) {
    double s = 0.0;
    unsigned long long c = 0ull;
    for (int idx = threadIdx.x; idx < NBLOCK; idx += 256) {
        s += (double)pce[idx];
        c += pcnt[idx];
    }
    #pragma unroll
    for (int off = 32; off > 0; off >>= 1) {
        s += __shfl_xor(s, off, 64);
        c += __shfl_xor(c, off, 64);
    }
    __shared__ double sd[4];
    __shared__ unsigned long long sc[4];
    const int lane = threadIdx.x & 63, wv = threadIdx.x >> 6;
    if (lane == 0) { sd[wv] = s; sc[wv] = c; }
    __syncthreads();
    if (threadIdx.x == 0) {
        const double st = sd[0] + sd[1] + sd[2] + sd[3];
        const unsigned long long ct = sc[0] + sc[1] + sc[2] + sc[3];
        const double denom = (double)NN * (NN - 1) * LL * BB;   // 507904
        const double multi = (double)BB * NN * (NN - 1);        // 7936
        out[0] = (float)(st / denom);
        out[1] = (float)((double)(unsigned int)(ct & 0xffffffffull) / denom);
        out[2] = (float)((double)(ct >> 32) / multi);
    }
}

extern "C" void kernel_launch(void* const* d_in, const int* in_sizes, int n_in,
                              void* d_out, int out_size, void* d_ws, size_t ws_size,
                              hipStream_t stream) {
    const float* probs  = (const float*)d_in[0];
    const int*   target = (const int*)d_in[1];
    float* pce = (float*)d_ws;                                        // 2048 floats
    unsigned long long* pcnt = (unsigned long long*)((char*)d_ws + 8192); // 2048 u64

    fsmre_main<<<dim3(NBLOCK), dim3(256), 0, stream>>>(probs, target, pce, pcnt);
    fsmre_final<<<dim3(1), dim3(256), 0, stream>>>(pce, pcnt, (float*)d_out);
}